// Round 1
// baseline (10908.393 us; speedup 1.0000x reference)
//
#include <hip/hip_runtime.h>
#include <math.h>

// ---------------------------------------------------------------------------
// DenoiseLSTM: B=32, S=T=128, D_EMB=128, D_ENC=256, D_DEC=512, V=32000
//
//  k_init : zero grid-barrier, gather embeddings, init h0 states
//  k_pre  : batched x@Wih^T + biases (time-parallel)
//  k_rec  : persistent 64-WG kernel. Weights cached in LDS once/phase;
//           per step: stage h->LDS (swizzled), 8b x 8row register-tile MAC,
//           in-wave butterfly reduce-scatter (shfl_xor), per-thread cell.
//  k_attn : batch-parallel attention
//  k_f1   : [4096,1024]@W_f1^T + b, lrelu
//  k_out  : [4096,512]@W_f2^T -> logits (dominant fp32 GEMM)
// ---------------------------------------------------------------------------

#define NWG 64

// workspace layout (float offsets)
constexpr size_t OFF_EMBS = 16;                      // [128 s][32 b][128 e]
constexpr size_t OFF_DEMB = OFF_EMBS + 524288;       // [128 t][32 b][128 e]
constexpr size_t OFF_PREF = OFF_DEMB + 524288;       // [128 s][1024 g][32 b]
constexpr size_t OFF_PREB = OFF_PREF + 4194304;      // [128 s][1024 g][32 b]
constexpr size_t OFF_PRED = OFF_PREB + 4194304;      // [128 t][2048 g][32 b]
constexpr size_t OFF_HENC = OFF_PRED + 8388608;      // [2 dir][2 buf][32 b][256]
constexpr size_t OFF_CFIN = OFF_HENC + 32768;        // [32 b][512]
constexpr size_t OFF_CDEC = OFF_CFIN + 16384;        // [32 b][512]
constexpr size_t OFF_HD   = OFF_CDEC + 16384;        // [2 buf][32 b][512]
constexpr size_t OFF_MEM  = OFF_HD + 32768;          // [32 b][128 s][512]
constexpr size_t OFF_FFN  = OFF_MEM + 2097152;       // [4096 row=t*32+b][1024]
constexpr size_t OFF_F1   = OFF_FFN + 4194304;       // [4096][512]

__device__ __forceinline__ float sigm(float x)  { return 1.0f / (1.0f + expf(-x)); }
__device__ __forceinline__ float lrelu(float x) { return x >= 0.0f ? x : 0.1f * x; }
__device__ __forceinline__ float dot4(float4 a, float4 b) {
  return a.x*b.x + a.y*b.y + a.z*b.z + a.w*b.w;
}

// device-scope grid barrier (proven in round 1)
__device__ __forceinline__ void gsync(unsigned* bar, unsigned& epoch) {
  __syncthreads();
  if (threadIdx.x == 0) {
    __threadfence();
    epoch += NWG;
    atomicAdd(bar, 1u);
    while (__hip_atomic_load(bar, __ATOMIC_ACQUIRE, __HIP_MEMORY_SCOPE_AGENT) < epoch) {
      __builtin_amdgcn_s_sleep(2);
    }
    __threadfence();
  }
  __syncthreads();
}

// ---------------------------------------------------------------------------
__global__ __launch_bounds__(256) void k_init(
    const int* __restrict__ inp, const int* __restrict__ x,
    const int* __restrict__ label_i, const int* __restrict__ label,
    const float* __restrict__ start_emb, const float* __restrict__ tok_emb,
    const float* __restrict__ enc_style, const float* __restrict__ style,
    float* __restrict__ ws)
{
  const size_t stride = (size_t)gridDim.x * 256;
  const size_t i0 = (size_t)blockIdx.x * 256 + threadIdx.x;
  if (i0 == 0) *((unsigned*)ws) = 0u;

  for (size_t i = i0; i < 524288; i += stride) {
    int row = (int)(i >> 7), e = (int)(i & 127);
    int s = row >> 5, bb = row & 31;
    ws[OFF_EMBS + i] = tok_emb[(size_t)inp[bb*128 + s] * 128 + e];
    ws[OFF_DEMB + i] = (s == 0) ? start_emb[e]
                                : tok_emb[(size_t)x[bb*128 + (s-1)] * 128 + e];
  }
  for (size_t i = i0; i < 16384; i += stride) {
    int dir = (int)(i >> 13);
    int bb  = (int)((i >> 8) & 31);
    int j   = (int)(i & 255);
    ws[OFF_HENC + (size_t)(dir*2)*8192 + (size_t)bb*256 + j] =
        enc_style[(size_t)label_i[bb]*512 + dir*256 + j];
  }
  for (size_t i = i0; i < 16384; i += stride) {
    int bb = (int)(i >> 9), k = (int)(i & 511);
    ws[OFF_HD + (size_t)bb*512 + k] = style[(size_t)label[bb]*512 + k];
  }
}

// ---------------------------------------------------------------------------
// pre[t][g][b] = (bih+bhh)[g] + sum_e X[xrow(t,b)][e] * W[g][e]
__global__ __launch_bounds__(256) void k_pre(
    const float* __restrict__ X, const float* __restrict__ W,
    const float* __restrict__ b1, const float* __restrict__ b2,
    float* __restrict__ outp, int G, int rev)
{
  const int ntile = G >> 6;
  const int t  = blockIdx.x / ntile;
  const int gt = blockIdx.x - t * ntile;
  const int tid = threadIdx.x;
  const int b = tid & 31, gi = tid >> 5;
  const int g0 = gt * 64 + gi * 8;
  const int xt = rev ? (127 - t) : t;
  const float* xr = X + (size_t)(xt*32 + b) * 128;

  float acc[8];
  #pragma unroll
  for (int q = 0; q < 8; ++q) acc[q] = b1[g0+q] + b2[g0+q];

  for (int e = 0; e < 128; e += 4) {
    float4 x4 = *(const float4*)&xr[e];
    #pragma unroll
    for (int q = 0; q < 8; ++q) {
      float4 w4 = *(const float4*)&W[(size_t)(g0+q)*128 + e];
      acc[q] += dot4(x4, w4);
    }
  }
  float* o = outp + (size_t)t * G * 32;
  #pragma unroll
  for (int q = 0; q < 8; ++q) o[(size_t)(g0+q)*32 + b] = acc[q];
}

// ---------------------------------------------------------------------------
// k_rec helpers
// ---------------------------------------------------------------------------
template<int R>  // R = H/4 (f4 per h-row): 64 (enc) or 128 (dec)
__device__ __forceinline__ void stage_h(const float4* __restrict__ hsrc4,
                                        float4* Hl4, int tid)
{
  constexpr int LB = (R == 128) ? 7 : 6;
  #pragma unroll
  for (int u = 0; u < (32*R)/256; ++u) {
    int g = u*256 + tid;
    int b = g >> LB, k4 = g & (R - 1);
    Hl4[b*R + (k4 ^ (k4 >> 3))] = hsrc4[g];
  }
}

template<int R>
__device__ __forceinline__ void mac8x8(const float4* Hl4, const float4* Wl4,
                                       int bg, int ks, int jg, int mm,
                                       float acc[8][8])
{
  constexpr int KC = R / 16;  // f4 per thread k-chunk: 4 (enc) / 8 (dec)
  #pragma unroll
  for (int kk = 0; kk < KC; ++kk) {
    int k4 = ks*KC + kk;
    int sz = k4 ^ (k4 >> 3);
    float4 h4[8], w4[8];
    #pragma unroll
    for (int i = 0; i < 8; ++i) h4[i] = Hl4[(bg*8 + i)*R + sz];
    #pragma unroll
    for (int r = 0; r < 8; ++r) w4[r] = Wl4[(jg*8 + r)*R + (sz ^ mm)];
    #pragma unroll
    for (int i = 0; i < 8; ++i)
      #pragma unroll
      for (int r = 0; r < 8; ++r)
        acc[i][r] += h4[i].x*w4[r].x + h4[i].y*w4[r].y
                   + h4[i].z*w4[r].z + h4[i].w*w4[r].w;
  }
}

// reduce-scatter butterfly step: keep upper half if bit set, exchange the rest
template<int HALF, int MASK>
__device__ __forceinline__ void bstep(float* v, int bit) {
  #pragma unroll
  for (int u = 0; u < HALF; ++u) {
    float give = bit ? v[u] : v[u + HALF];
    float got  = __shfl_xor(give, MASK, 64);
    float mine = bit ? v[u + HALF] : v[u];
    v[u] = mine + got;
  }
}

// ---------------------------------------------------------------------------
// persistent recurrence kernel: 64 WGs x 256 threads
// thread id decomposition: bg = tid>>6 (wave), ks = (tid>>2)&15, jg = tid&3
// cell ownership: b = bg*8 + (ks>>1), j_local = jg*2 + (ks&1)
__global__ __launch_bounds__(256, 1) void k_rec(
    const float* __restrict__ Whh_f, const float* __restrict__ Whh_b,
    const float* __restrict__ Whh_d, const float* __restrict__ W_tr,
    float* __restrict__ ws)
{
  __shared__ float4 Wl4[4096];   // 64 KB: weight slice (swizzled)
  __shared__ float4 Hl4[4096];   // 64 KB: h staging (swizzled)
  unsigned* bar = (unsigned*)ws;
  unsigned epoch = 0;
  const int wg = blockIdx.x, tid = threadIdx.x;
  const int bg = tid >> 6, ks = (tid >> 2) & 15, jg = tid & 3;
  const int mm = jg ^ ((jg & 1) << 2);
  const int cb  = bg*8 + (ks >> 1);     // cell batch row
  const int cjl = jg*2 + (ks & 1);      // cell j within WG's 8-slice

  float* henc = ws + OFF_HENC;
  float* cfin = ws + OFF_CFIN;
  float* cdec = ws + OFF_CDEC;
  float* hd   = ws + OFF_HD;
  float* mem  = ws + OFF_MEM;
  float* ffn  = ws + OFF_FFN;

  // ---------------- encoder (fwd: wg 0..31, bwd: wg 32..63) ----------------
  {
    const int dir = wg >> 5;
    const int j0  = (wg & 31) * 8;
    const float* Whh = dir ? Whh_b : Whh_f;
    const float* pre = dir ? (ws + OFF_PREB) : (ws + OFF_PREF);

    // stage weight slice once: 32 rows (row = jl*4+gate) x 64 f4
    #pragma unroll
    for (int u = 0; u < 8; ++u) {
      int idx = u*256 + tid, row = idx >> 6, k4 = idx & 63;
      int gate = row & 3, jl_ = row >> 2;
      int m = row >> 3, mw = m ^ ((m & 1) << 2);
      Wl4[row*64 + ((k4 ^ (k4 >> 3)) ^ mw)] =
          ((const float4*)Whh)[(size_t)(gate*256 + j0 + jl_)*64 + k4];
    }

    const int j = j0 + cjl;
    float c = 0.0f;

    for (int s = 0; s < 128; ++s) {
      const float* prep = pre + (size_t)s * 32768;
      float pg[4];
      #pragma unroll
      for (int g = 0; g < 4; ++g) pg[g] = prep[(size_t)(g*256 + j)*32 + cb];

      stage_h<64>((const float4*)(henc + (size_t)(dir*2 + (s & 1))*8192), Hl4, tid);
      __syncthreads();

      float acc[8][8] = {};
      mac8x8<64>(Hl4, Wl4, bg, ks, jg, mm, acc);

      float* v = &acc[0][0];
      bstep<32,32>(v, (ks >> 3) & 1);
      bstep<16,16>(v, (ks >> 2) & 1);
      bstep<8, 8 >(v, (ks >> 1) & 1);
      bstep<4, 4 >(v, ks & 1);
      // v[0..3] = recurrent gate sums (i,f,g,o) for cell (cb, j)

      float gi = pg[0] + v[0], gf = pg[1] + v[1];
      float gg = pg[2] + v[2], go = pg[3] + v[3];
      c = sigm(gf)*c + sigm(gi)*tanhf(gg);
      float h = sigm(go)*tanhf(c);

      henc[(size_t)(dir*2 + ((s+1) & 1))*8192 + (size_t)cb*256 + j] = h;
      int spos = dir ? (127 - s) : s;
      mem[((size_t)cb*128 + spos)*512 + dir*256 + j] = h;
      gsync(bar, epoch);
    }
    cfin[(size_t)cb*512 + dir*256 + j] = c;
    gsync(bar, epoch);
  }

  // ---------------- transition: c_t = lrelu([cf|cb] @ W_tr^T) ----------------
  {
    // stage W_tr rows [wg*8, wg*8+8): 8 x 128 f4 (mm = 0 since row>>3 == 0)
    #pragma unroll
    for (int u = 0; u < 4; ++u) {
      int idx = u*256 + tid, row = idx >> 7, k4 = idx & 127;
      Wl4[row*128 + (k4 ^ (k4 >> 3))] =
          ((const float4*)W_tr)[(size_t)(wg*8 + row)*128 + k4];
    }
    stage_h<128>((const float4*)cfin, Hl4, tid);
    __syncthreads();

    float acc[8][8] = {};
    #pragma unroll
    for (int e = 0; e < 2; ++e) {
      int k4 = (ks*4 + jg)*2 + e;   // 64-way k-split, 2 f4 each
      int sz = k4 ^ (k4 >> 3);
      float4 h4[8], w4[8];
      #pragma unroll
      for (int i = 0; i < 8; ++i) h4[i] = Hl4[(bg*8 + i)*128 + sz];
      #pragma unroll
      for (int r = 0; r < 8; ++r) w4[r] = Wl4[r*128 + sz];
      #pragma unroll
      for (int i = 0; i < 8; ++i)
        #pragma unroll
        for (int r = 0; r < 8; ++r)
          acc[i][r] += dot4(h4[i], w4[r]);
    }
    float* v = &acc[0][0];
    bstep<32,32>(v, (ks >> 3) & 1);
    bstep<16,16>(v, (ks >> 2) & 1);
    bstep<8, 8 >(v, (ks >> 1) & 1);
    bstep<4, 4 >(v, ks & 1);
    bstep<2, 2 >(v, (jg >> 1) & 1);
    bstep<1, 1 >(v, jg & 1);
    int ml = (ks & 1)*4 + jg;
    cdec[(size_t)(bg*8 + (ks >> 1))*512 + wg*8 + ml] = lrelu(v[0]);
    gsync(bar, epoch);
  }

  // ---------------- decoder LSTM ----------------
  {
    const int j0 = wg * 8;
    // stage weight slice: 32 rows x 128 f4
    #pragma unroll
    for (int u = 0; u < 16; ++u) {
      int idx = u*256 + tid, row = idx >> 7, k4 = idx & 127;
      int gate = row & 3, jl_ = row >> 2;
      int m = row >> 3, mw = m ^ ((m & 1) << 2);
      Wl4[row*128 + ((k4 ^ (k4 >> 3)) ^ mw)] =
          ((const float4*)Whh_d)[(size_t)(gate*512 + j0 + jl_)*128 + k4];
    }

    const int j = j0 + cjl;
    float c = cdec[(size_t)cb*512 + j];
    const float* preD = ws + OFF_PRED;

    for (int t = 0; t < 128; ++t) {
      const float* prep = preD + (size_t)t * 65536;
      float pg[4];
      #pragma unroll
      for (int g = 0; g < 4; ++g) pg[g] = prep[(size_t)(g*512 + j)*32 + cb];

      stage_h<128>((const float4*)(hd + (size_t)(t & 1)*16384), Hl4, tid);
      __syncthreads();

      float acc[8][8] = {};
      mac8x8<128>(Hl4, Wl4, bg, ks, jg, mm, acc);

      float* v = &acc[0][0];
      bstep<32,32>(v, (ks >> 3) & 1);
      bstep<16,16>(v, (ks >> 2) & 1);
      bstep<8, 8 >(v, (ks >> 1) & 1);
      bstep<4, 4 >(v, ks & 1);

      float gi = pg[0] + v[0], gf = pg[1] + v[1];
      float gg = pg[2] + v[2], go = pg[3] + v[3];
      c = sigm(gf)*c + sigm(gi)*tanhf(gg);
      float h = sigm(go)*tanhf(c);

      hd[(size_t)((t+1) & 1)*16384 + (size_t)cb*512 + j] = h;
      ffn[((size_t)t*32 + cb)*1024 + j] = h;
      gsync(bar, epoch);
    }
  }
}

// ---------------------------------------------------------------------------
// attention for all (t,b): wg = (b, 16-t chunk). scores -> softmax -> ctx
__global__ __launch_bounds__(256) void k_attn(float* __restrict__ ws)
{
  const int b  = blockIdx.x >> 3;
  const int t0 = (blockIdx.x & 7) * 16;
  __shared__ float Hc[16*64];
  __shared__ float Mc[128*68];
  __shared__ float Sc[16*132];
  const int tid = threadIdx.x;
  const float* mem = ws + OFF_MEM;
  float* ffn = ws + OFF_FFN;
  const int r  = tid >> 4;
  const int si = tid & 15;
  const float scale = 0.044194173824159216f;   // 1/sqrt(512)

  float acc[8];
  #pragma unroll
  for (int q = 0; q < 8; ++q) acc[q] = 0.0f;

  for (int dc = 0; dc < 8; ++dc) {
    const int d0 = dc * 64;
    __syncthreads();
    { int rr = tid >> 4, dd = (tid & 15) * 4;
      *(float4*)&Hc[rr*64 + dd] =
          *(const float4*)&ffn[((size_t)(t0+rr)*32 + b)*1024 + d0 + dd]; }
    { int s = tid >> 1, half = (tid & 1) * 32;
      const float* src = &mem[((size_t)b*128 + s)*512 + d0 + half];
      #pragma unroll
      for (int u = 0; u < 8; ++u)
        *(float4*)&Mc[s*68 + half + u*4] = *(const float4*)&src[u*4]; }
    __syncthreads();
    #pragma unroll 4
    for (int kk = 0; kk < 64; kk += 4) {
      float4 h4 = *(const float4*)&Hc[r*64 + kk];
      #pragma unroll
      for (int q = 0; q < 8; ++q) {
        float4 m4 = *(const float4*)&Mc[(si + 16*q)*68 + kk];
        acc[q] += dot4(h4, m4);
      }
    }
  }
  #pragma unroll
  for (int q = 0; q < 8; ++q) Sc[r*132 + si + 16*q] = acc[q] * scale;
  __syncthreads();

  {
    const int w = tid >> 6, lane = tid & 63;
    for (int rr = w*4; rr < w*4 + 4; ++rr) {
      float v0 = Sc[rr*132 + lane];
      float v1 = Sc[rr*132 + 64 + lane];
      float m = fmaxf(v0, v1);
      #pragma unroll
      for (int off = 32; off >= 1; off >>= 1) m = fmaxf(m, __shfl_xor(m, off));
      float e0 = expf(v0 - m), e1 = expf(v1 - m);
      float ssum = e0 + e1;
      #pragma unroll
      for (int off = 32; off >= 1; off >>= 1) ssum += __shfl_xor(ssum, off);
      float inv = 1.0f / ssum;
      Sc[rr*132 + lane]      = e0 * inv;
      Sc[rr*132 + 64 + lane] = e1 * inv;
    }
  }

  for (int dc = 0; dc < 8; ++dc) {
    const int d0 = dc * 64;
    __syncthreads();
    { int s = tid >> 1, half = (tid & 1) * 32;
      const float* src = &mem[((size_t)b*128 + s)*512 + d0 + half];
      #pragma unroll
      for (int u = 0; u < 8; ++u)
        *(float4*)&Mc[s*68 + half + u*4] = *(const float4*)&src[u*4]; }
    __syncthreads();
    const int dd = (tid & 15) * 4;
    float4 a4; a4.x = a4.y = a4.z = a4.w = 0.0f;
    for (int s = 0; s < 128; s += 4) {
      float4 p4 = *(const float4*)&Sc[r*132 + s];
      float4 m0 = *(const float4*)&Mc[(s+0)*68 + dd];
      float4 m1 = *(const float4*)&Mc[(s+1)*68 + dd];
      float4 m2 = *(const float4*)&Mc[(s+2)*68 + dd];
      float4 m3 = *(const float4*)&Mc[(s+3)*68 + dd];
      a4.x += p4.x*m0.x + p4.y*m1.x + p4.z*m2.x + p4.w*m3.x;
      a4.y += p4.x*m0.y + p4.y*m1.y + p4.z*m2.y + p4.w*m3.y;
      a4.z += p4.x*m0.z + p4.y*m1.z + p4.z*m2.z + p4.w*m3.z;
      a4.w += p4.x*m0.w + p4.y*m1.w + p4.z*m2.w + p4.w*m3.w;
    }
    *(float4*)&ffn[((size_t)(t0+r)*32 + b)*1024 + 512 + d0 + dd] = a4;
  }
}

// ---------------------------------------------------------------------------
// f1out = lrelu(ffn @ W_f1^T + b_f1)   [4096,1024]@[1024,512]
__global__ __launch_bounds__(256) void k_f1(
    const float* __restrict__ A, const float* __restrict__ Bm,
    const float* __restrict__ bias, float* __restrict__ out)
{
  const int rt = blockIdx.x >> 2;
  const int vt = blockIdx.x & 3;
  __shared__ float As[64*44];
  __shared__ float Bs[128*44];
  const int tid = threadIdx.x, tx = tid & 15, ty = tid >> 4;
  float acc[4][8];
  #pragma unroll
  for (int i = 0; i < 4; ++i)
    #pragma unroll
    for (int j = 0; j < 8; ++j) acc[i][j] = 0.0f;

  for (int k0 = 0; k0 < 1024; k0 += 32) {
    __syncthreads();
    { int r = tid >> 2, kp = (tid & 3) * 8;
      const float* src = A + (size_t)(rt*64 + r)*1024 + k0 + kp;
      *(float4*)&As[r*44 + kp]     = ((const float4*)src)[0];
      *(float4*)&As[r*44 + kp + 4] = ((const float4*)src)[1]; }
    { int v = tid >> 1, kp = (tid & 1) * 16;
      const float* src = Bm + (size_t)(vt*128 + v)*1024 + k0 + kp;
      *(float4*)&Bs[v*44 + kp]      = ((const float4*)src)[0];
      *(float4*)&Bs[v*44 + kp + 4]  = ((const float4*)src)[1];
      *(float4*)&Bs[v*44 + kp + 8]  = ((const float4*)src)[2];
      *(float4*)&Bs[v*44 + kp + 12] = ((const float4*)src)[3]; }
    __syncthreads();
    #pragma unroll
    for (int kk = 0; kk < 32; kk += 4) {
      float4 a4[4], b4[8];
      #pragma unroll
      for (int i = 0; i < 4; ++i) a4[i] = *(const float4*)&As[(ty + 16*i)*44 + kk];
      #pragma unroll
      for (int j = 0; j < 8; ++j) b4[j] = *(const float4*)&Bs[(tx + 16*j)*44 + kk];
      #pragma unroll
      for (int i = 0; i < 4; ++i)
        #pragma unroll
        for (int j = 0; j < 8; ++j)
          acc[i][j] += dot4(a4[i], b4[j]);
    }
  }
  #pragma unroll
  for (int i = 0; i < 4; ++i) {
    int r = rt*64 + ty + 16*i;
    #pragma unroll
    for (int j = 0; j < 8; ++j) {
      int v = vt*128 + tx + 16*j;
      out[(size_t)r*512 + v] = lrelu(acc[i][j] + bias[v]);
    }
  }
}

// ---------------------------------------------------------------------------
// logits = f1out @ W_f2^T -> out[b][t][v]   [4096,512]@[512,32000]
__global__ __launch_bounds__(256, 2) void k_out(
    const float* __restrict__ A, const float* __restrict__ Bm,
    float* __restrict__ out)
{
  const int rt = blockIdx.x & 63;
  const int vt = blockIdx.x >> 6;
  __shared__ float As[64*44];
  __shared__ float Bs[128*44];
  const int tid = threadIdx.x, tx = tid & 15, ty = tid >> 4;
  float acc[4][8];
  #pragma unroll
  for (int i = 0; i < 4; ++i)
    #pragma unroll
    for (int j = 0; j < 8; ++j) acc[i][j] = 0.0f;

  for (int k0 = 0; k0 < 512; k0 += 32) {
    __syncthreads();
    { int r = tid >> 2, kp = (tid & 3) * 8;
      const float* src = A + (size_t)(rt*64 + r)*512 + k0 + kp;
      *(float4*)&As[r*44 + kp]     = ((const float4*)src)[0];
      *(float4*)&As[r*44 + kp + 4] = ((const float4*)src)[1]; }
    { int v = tid >> 1, kp = (tid & 1) * 16;
      const float* src = Bm + (size_t)(vt*128 + v)*512 + k0 + kp;
      *(float4*)&Bs[v*44 + kp]      = ((const float4*)src)[0];
      *(float4*)&Bs[v*44 + kp + 4]  = ((const float4*)src)[1];
      *(float4*)&Bs[v*44 + kp + 8]  = ((const float4*)src)[2];
      *(float4*)&Bs[v*44 + kp + 12] = ((const float4*)src)[3]; }
    __syncthreads();
    #pragma unroll
    for (int kk = 0; kk < 32; kk += 4) {
      float4 a4[4], b4[8];
      #pragma unroll
      for (int i = 0; i < 4; ++i) a4[i] = *(const float4*)&As[(ty + 16*i)*44 + kk];
      #pragma unroll
      for (int j = 0; j < 8; ++j) b4[j] = *(const float4*)&Bs[(tx + 16*j)*44 + kk];
      #pragma unroll
      for (int i = 0; i < 4; ++i)
        #pragma unroll
        for (int j = 0; j < 8; ++j)
          acc[i][j] += dot4(a4[i], b4[j]);
    }
  }
  #pragma unroll
  for (int i = 0; i < 4; ++i) {
    int n = rt*64 + ty + 16*i;           // row = t*32 + b
    int bb = n & 31, t = n >> 5;
    float* orow = out + ((size_t)bb*128 + t)*32000 + (size_t)vt*128;
    #pragma unroll
    for (int j = 0; j < 8; ++j) orow[tx + 16*j] = acc[i][j];
  }
}

// ---------------------------------------------------------------------------
extern "C" void kernel_launch(void* const* d_in, const int* in_sizes, int n_in,
                              void* d_out, int out_size, void* d_ws, size_t ws_size,
                              hipStream_t stream)
{
  (void)in_sizes; (void)n_in; (void)out_size; (void)ws_size;
  const int*   inp     = (const int*)d_in[0];
  const int*   label_i = (const int*)d_in[1];
  const int*   x       = (const int*)d_in[2];
  const int*   label   = (const int*)d_in[3];
  const float* start_e = (const float*)d_in[4];
  const float* tok_emb = (const float*)d_in[5];
  const float* enc_sty = (const float*)d_in[6];
  const float* style   = (const float*)d_in[7];
  const float* Wih_f   = (const float*)d_in[8];
  const float* Whh_f   = (const float*)d_in[9];
  const float* bih_f   = (const float*)d_in[10];
  const float* bhh_f   = (const float*)d_in[11];
  const float* Wih_b   = (const float*)d_in[12];
  const float* Whh_b   = (const float*)d_in[13];
  const float* bih_b   = (const float*)d_in[14];
  const float* bhh_b   = (const float*)d_in[15];
  const float* Wih_d   = (const float*)d_in[16];
  const float* Whh_d   = (const float*)d_in[17];
  const float* bih_d   = (const float*)d_in[18];
  const float* bhh_d   = (const float*)d_in[19];
  const float* W_tr    = (const float*)d_in[20];
  const float* W_f1    = (const float*)d_in[21];
  const float* b_f1    = (const float*)d_in[22];
  const float* W_f2    = (const float*)d_in[23];
  float* ws  = (float*)d_ws;
  float* out = (float*)d_out;

  k_init<<<dim3(1024), dim3(256), 0, stream>>>(inp, x, label_i, label,
                                               start_e, tok_emb, enc_sty, style, ws);
  k_pre<<<dim3(2048), dim3(256), 0, stream>>>(ws + OFF_EMBS, Wih_f, bih_f, bhh_f,
                                              ws + OFF_PREF, 1024, 0);
  k_pre<<<dim3(2048), dim3(256), 0, stream>>>(ws + OFF_EMBS, Wih_b, bih_b, bhh_b,
                                              ws + OFF_PREB, 1024, 1);
  k_pre<<<dim3(4096), dim3(256), 0, stream>>>(ws + OFF_DEMB, Wih_d, bih_d, bhh_d,
                                              ws + OFF_PRED, 2048, 0);
  k_rec<<<dim3(NWG), dim3(256), 0, stream>>>(Whh_f, Whh_b, Whh_d, W_tr, ws);
  k_attn<<<dim3(256), dim3(256), 0, stream>>>(ws);
  k_f1<<<dim3(256), dim3(256), 0, stream>>>(ws + OFF_FFN, W_f1, b_f1, ws + OFF_F1);
  k_out<<<dim3(16000), dim3(256), 0, stream>>>(ws + OFF_F1, W_f2, out);
}

// Round 3
// 6828.123 us; speedup vs baseline: 1.5976x; 1.5976x over previous
//
#include <hip/hip_runtime.h>
#include <math.h>

// ---------------------------------------------------------------------------
// DenoiseLSTM: B=32, S=T=128, D_EMB=128, D_ENC=256, D_DEC=512, V=32000
//
//  k_init : zero grid-barrier, gather embeddings, init h0 states
//  k_pre  : batched x@Wih^T + biases (time-parallel)
//  k_rec  : persistent 64-WG kernel (encoder/transition/decoder recurrence)
//  k_attn : batch-parallel attention
//  k_f1   : [4096,1024]@W_f1^T + b, lrelu -> split-bf16 (Ahi/Alo)
//  k_cvtW : W_f2 fp32 -> (Whi, Wlo) bf16 split (PREF/PRED regions, dead by then)
//  k_out2 : MFMA 3-pass split-bf16 GEMM: C = Ahi*Whi^T + Ahi*Wlo^T + Alo*Whi^T
// ---------------------------------------------------------------------------

#define NWG 64

typedef unsigned short u16;
typedef unsigned int   u32;
typedef __attribute__((ext_vector_type(8))) short s16x8;   // 8 bf16 (4 VGPRs)
typedef __attribute__((ext_vector_type(4))) float f32x4;   // MFMA acc
typedef __attribute__((ext_vector_type(8))) u16   u16x8;

// workspace layout (float offsets)
constexpr size_t OFF_EMBS = 16;                      // [128 s][32 b][128 e]
constexpr size_t OFF_DEMB = OFF_EMBS + 524288;       // [128 t][32 b][128 e]
constexpr size_t OFF_PREF = OFF_DEMB + 524288;       // [128 s][1024 g][32 b]
constexpr size_t OFF_PREB = OFF_PREF + 4194304;      // [128 s][1024 g][32 b]
constexpr size_t OFF_PRED = OFF_PREB + 4194304;      // [128 t][2048 g][32 b]
constexpr size_t OFF_HENC = OFF_PRED + 8388608;      // [2 dir][2 buf][32 b][256]
constexpr size_t OFF_CFIN = OFF_HENC + 32768;        // [32 b][512]
constexpr size_t OFF_CDEC = OFF_CFIN + 16384;        // [32 b][512]
constexpr size_t OFF_HD   = OFF_CDEC + 16384;        // [2 buf][32 b][512]
constexpr size_t OFF_MEM  = OFF_HD + 32768;          // [32 b][128 s][512]
constexpr size_t OFF_FFN  = OFF_MEM + 2097152;       // [4096 row=t*32+b][1024]
constexpr size_t OFF_F1   = OFF_FFN + 4194304;       // [4096][512] -> Ahi/Alo bf16

__device__ __forceinline__ float sigm(float x)  { return 1.0f / (1.0f + expf(-x)); }
__device__ __forceinline__ float lrelu(float x) { return x >= 0.0f ? x : 0.1f * x; }
__device__ __forceinline__ float dot4(float4 a, float4 b) {
  return a.x*b.x + a.y*b.y + a.z*b.z + a.w*b.w;
}

// round-to-nearest-even float->bf16
__device__ __forceinline__ u16 f2bf(float x) {
  u32 u = __float_as_uint(x);
  u = (u + 0x7FFFu + ((u >> 16) & 1u)) >> 16;
  return (u16)u;
}
__device__ __forceinline__ float bf2f(u16 h) {
  return __uint_as_float(((u32)h) << 16);
}

// device-scope grid barrier (proven in round 1)
__device__ __forceinline__ void gsync(unsigned* bar, unsigned& epoch) {
  __syncthreads();
  if (threadIdx.x == 0) {
    __threadfence();
    epoch += NWG;
    atomicAdd(bar, 1u);
    while (__hip_atomic_load(bar, __ATOMIC_ACQUIRE, __HIP_MEMORY_SCOPE_AGENT) < epoch) {
      __builtin_amdgcn_s_sleep(2);
    }
    __threadfence();
  }
  __syncthreads();
}

// ---------------------------------------------------------------------------
__global__ __launch_bounds__(256) void k_init(
    const int* __restrict__ inp, const int* __restrict__ x,
    const int* __restrict__ label_i, const int* __restrict__ label,
    const float* __restrict__ start_emb, const float* __restrict__ tok_emb,
    const float* __restrict__ enc_style, const float* __restrict__ style,
    float* __restrict__ ws)
{
  const size_t stride = (size_t)gridDim.x * 256;
  const size_t i0 = (size_t)blockIdx.x * 256 + threadIdx.x;
  if (i0 == 0) *((unsigned*)ws) = 0u;

  for (size_t i = i0; i < 524288; i += stride) {
    int row = (int)(i >> 7), e = (int)(i & 127);
    int s = row >> 5, bb = row & 31;
    ws[OFF_EMBS + i] = tok_emb[(size_t)inp[bb*128 + s] * 128 + e];
    ws[OFF_DEMB + i] = (s == 0) ? start_emb[e]
                                : tok_emb[(size_t)x[bb*128 + (s-1)] * 128 + e];
  }
  for (size_t i = i0; i < 16384; i += stride) {
    int dir = (int)(i >> 13);
    int bb  = (int)((i >> 8) & 31);
    int j   = (int)(i & 255);
    ws[OFF_HENC + (size_t)(dir*2)*8192 + (size_t)bb*256 + j] =
        enc_style[(size_t)label_i[bb]*512 + dir*256 + j];
  }
  for (size_t i = i0; i < 16384; i += stride) {
    int bb = (int)(i >> 9), k = (int)(i & 511);
    ws[OFF_HD + (size_t)bb*512 + k] = style[(size_t)label[bb]*512 + k];
  }
}

// ---------------------------------------------------------------------------
// pre[t][g][b] = (bih+bhh)[g] + sum_e X[xrow(t,b)][e] * W[g][e]
__global__ __launch_bounds__(256) void k_pre(
    const float* __restrict__ X, const float* __restrict__ W,
    const float* __restrict__ b1, const float* __restrict__ b2,
    float* __restrict__ outp, int G, int rev)
{
  const int ntile = G >> 6;
  const int t  = blockIdx.x / ntile;
  const int gt = blockIdx.x - t * ntile;
  const int tid = threadIdx.x;
  const int b = tid & 31, gi = tid >> 5;
  const int g0 = gt * 64 + gi * 8;
  const int xt = rev ? (127 - t) : t;
  const float* xr = X + (size_t)(xt*32 + b) * 128;

  float acc[8];
  #pragma unroll
  for (int q = 0; q < 8; ++q) acc[q] = b1[g0+q] + b2[g0+q];

  for (int e = 0; e < 128; e += 4) {
    float4 x4 = *(const float4*)&xr[e];
    #pragma unroll
    for (int q = 0; q < 8; ++q) {
      float4 w4 = *(const float4*)&W[(size_t)(g0+q)*128 + e];
      acc[q] += dot4(x4, w4);
    }
  }
  float* o = outp + (size_t)t * G * 32;
  #pragma unroll
  for (int q = 0; q < 8; ++q) o[(size_t)(g0+q)*32 + b] = acc[q];
}

// ---------------------------------------------------------------------------
// k_rec helpers
// ---------------------------------------------------------------------------
template<int R>  // R = H/4 (f4 per h-row): 64 (enc) or 128 (dec)
__device__ __forceinline__ void stage_h(const float4* __restrict__ hsrc4,
                                        float4* Hl4, int tid)
{
  constexpr int LB = (R == 128) ? 7 : 6;
  #pragma unroll
  for (int u = 0; u < (32*R)/256; ++u) {
    int g = u*256 + tid;
    int b = g >> LB, k4 = g & (R - 1);
    Hl4[b*R + (k4 ^ (k4 >> 3))] = hsrc4[g];
  }
}

template<int R>
__device__ __forceinline__ void mac8x8(const float4* Hl4, const float4* Wl4,
                                       int bg, int ks, int jg, int mm,
                                       float acc[8][8])
{
  constexpr int KC = R / 16;  // f4 per thread k-chunk: 4 (enc) / 8 (dec)
  #pragma unroll
  for (int kk = 0; kk < KC; ++kk) {
    int k4 = ks*KC + kk;
    int sz = k4 ^ (k4 >> 3);
    float4 h4[8], w4[8];
    #pragma unroll
    for (int i = 0; i < 8; ++i) h4[i] = Hl4[(bg*8 + i)*R + sz];
    #pragma unroll
    for (int r = 0; r < 8; ++r) w4[r] = Wl4[(jg*8 + r)*R + (sz ^ mm)];
    #pragma unroll
    for (int i = 0; i < 8; ++i)
      #pragma unroll
      for (int r = 0; r < 8; ++r)
        acc[i][r] += h4[i].x*w4[r].x + h4[i].y*w4[r].y
                   + h4[i].z*w4[r].z + h4[i].w*w4[r].w;
  }
}

// reduce-scatter butterfly step: keep upper half if bit set, exchange the rest
template<int HALF, int MASK>
__device__ __forceinline__ void bstep(float* v, int bit) {
  #pragma unroll
  for (int u = 0; u < HALF; ++u) {
    float give = bit ? v[u] : v[u + HALF];
    float got  = __shfl_xor(give, MASK, 64);
    float mine = bit ? v[u + HALF] : v[u];
    v[u] = mine + got;
  }
}

// ---------------------------------------------------------------------------
// persistent recurrence kernel: 64 WGs x 256 threads
__global__ __launch_bounds__(256, 1) void k_rec(
    const float* __restrict__ Whh_f, const float* __restrict__ Whh_b,
    const float* __restrict__ Whh_d, const float* __restrict__ W_tr,
    float* __restrict__ ws)
{
  __shared__ float4 Wl4[4096];   // 64 KB: weight slice (swizzled)
  __shared__ float4 Hl4[4096];   // 64 KB: h staging (swizzled)
  unsigned* bar = (unsigned*)ws;
  unsigned epoch = 0;
  const int wg = blockIdx.x, tid = threadIdx.x;
  const int bg = tid >> 6, ks = (tid >> 2) & 15, jg = tid & 3;
  const int mm = jg ^ ((jg & 1) << 2);
  const int cb  = bg*8 + (ks >> 1);     // cell batch row
  const int cjl = jg*2 + (ks & 1);      // cell j within WG's 8-slice

  float* henc = ws + OFF_HENC;
  float* cfin = ws + OFF_CFIN;
  float* cdec = ws + OFF_CDEC;
  float* hd   = ws + OFF_HD;
  float* mem  = ws + OFF_MEM;
  float* ffn  = ws + OFF_FFN;

  // ---------------- encoder (fwd: wg 0..31, bwd: wg 32..63) ----------------
  {
    const int dir = wg >> 5;
    const int j0  = (wg & 31) * 8;
    const float* Whh = dir ? Whh_b : Whh_f;
    const float* pre = dir ? (ws + OFF_PREB) : (ws + OFF_PREF);

    #pragma unroll
    for (int u = 0; u < 8; ++u) {
      int idx = u*256 + tid, row = idx >> 6, k4 = idx & 63;
      int gate = row & 3, jl_ = row >> 2;
      int m = row >> 3, mw = m ^ ((m & 1) << 2);
      Wl4[row*64 + ((k4 ^ (k4 >> 3)) ^ mw)] =
          ((const float4*)Whh)[(size_t)(gate*256 + j0 + jl_)*64 + k4];
    }

    const int j = j0 + cjl;
    float c = 0.0f;

    for (int s = 0; s < 128; ++s) {
      const float* prep = pre + (size_t)s * 32768;
      float pg[4];
      #pragma unroll
      for (int g = 0; g < 4; ++g) pg[g] = prep[(size_t)(g*256 + j)*32 + cb];

      stage_h<64>((const float4*)(henc + (size_t)(dir*2 + (s & 1))*8192), Hl4, tid);
      __syncthreads();

      float acc[8][8] = {};
      mac8x8<64>(Hl4, Wl4, bg, ks, jg, mm, acc);

      float* v = &acc[0][0];
      bstep<32,32>(v, (ks >> 3) & 1);
      bstep<16,16>(v, (ks >> 2) & 1);
      bstep<8, 8 >(v, (ks >> 1) & 1);
      bstep<4, 4 >(v, ks & 1);

      float gi = pg[0] + v[0], gf = pg[1] + v[1];
      float gg = pg[2] + v[2], go = pg[3] + v[3];
      c = sigm(gf)*c + sigm(gi)*tanhf(gg);
      float h = sigm(go)*tanhf(c);

      henc[(size_t)(dir*2 + ((s+1) & 1))*8192 + (size_t)cb*256 + j] = h;
      int spos = dir ? (127 - s) : s;
      mem[((size_t)cb*128 + spos)*512 + dir*256 + j] = h;
      gsync(bar, epoch);
    }
    cfin[(size_t)cb*512 + dir*256 + j] = c;
    gsync(bar, epoch);
  }

  // ---------------- transition: c_t = lrelu([cf|cb] @ W_tr^T) ----------------
  {
    #pragma unroll
    for (int u = 0; u < 4; ++u) {
      int idx = u*256 + tid, row = idx >> 7, k4 = idx & 127;
      Wl4[row*128 + (k4 ^ (k4 >> 3))] =
          ((const float4*)W_tr)[(size_t)(wg*8 + row)*128 + k4];
    }
    stage_h<128>((const float4*)cfin, Hl4, tid);
    __syncthreads();

    float acc[8][8] = {};
    #pragma unroll
    for (int e = 0; e < 2; ++e) {
      int k4 = (ks*4 + jg)*2 + e;
      int sz = k4 ^ (k4 >> 3);
      float4 h4[8], w4[8];
      #pragma unroll
      for (int i = 0; i < 8; ++i) h4[i] = Hl4[(bg*8 + i)*128 + sz];
      #pragma unroll
      for (int r = 0; r < 8; ++r) w4[r] = Wl4[r*128 + sz];
      #pragma unroll
      for (int i = 0; i < 8; ++i)
        #pragma unroll
        for (int r = 0; r < 8; ++r)
          acc[i][r] += dot4(h4[i], w4[r]);
    }
    float* v = &acc[0][0];
    bstep<32,32>(v, (ks >> 3) & 1);
    bstep<16,16>(v, (ks >> 2) & 1);
    bstep<8, 8 >(v, (ks >> 1) & 1);
    bstep<4, 4 >(v, ks & 1);
    bstep<2, 2 >(v, (jg >> 1) & 1);
    bstep<1, 1 >(v, jg & 1);
    int ml = (ks & 1)*4 + jg;
    cdec[(size_t)(bg*8 + (ks >> 1))*512 + wg*8 + ml] = lrelu(v[0]);
    gsync(bar, epoch);
  }

  // ---------------- decoder LSTM ----------------
  {
    const int j0 = wg * 8;
    #pragma unroll
    for (int u = 0; u < 16; ++u) {
      int idx = u*256 + tid, row = idx >> 7, k4 = idx & 127;
      int gate = row & 3, jl_ = row >> 2;
      int m = row >> 3, mw = m ^ ((m & 1) << 2);
      Wl4[row*128 + ((k4 ^ (k4 >> 3)) ^ mw)] =
          ((const float4*)Whh_d)[(size_t)(gate*512 + j0 + jl_)*128 + k4];
    }

    const int j = j0 + cjl;
    float c = cdec[(size_t)cb*512 + j];
    const float* preD = ws + OFF_PRED;

    for (int t = 0; t < 128; ++t) {
      const float* prep = preD + (size_t)t * 65536;
      float pg[4];
      #pragma unroll
      for (int g = 0; g < 4; ++g) pg[g] = prep[(size_t)(g*512 + j)*32 + cb];

      stage_h<128>((const float4*)(hd + (size_t)(t & 1)*16384), Hl4, tid);
      __syncthreads();

      float acc[8][8] = {};
      mac8x8<128>(Hl4, Wl4, bg, ks, jg, mm, acc);

      float* v = &acc[0][0];
      bstep<32,32>(v, (ks >> 3) & 1);
      bstep<16,16>(v, (ks >> 2) & 1);
      bstep<8, 8 >(v, (ks >> 1) & 1);
      bstep<4, 4 >(v, ks & 1);

      float gi = pg[0] + v[0], gf = pg[1] + v[1];
      float gg = pg[2] + v[2], go = pg[3] + v[3];
      c = sigm(gf)*c + sigm(gi)*tanhf(gg);
      float h = sigm(go)*tanhf(c);

      hd[(size_t)((t+1) & 1)*16384 + (size_t)cb*512 + j] = h;
      ffn[((size_t)t*32 + cb)*1024 + j] = h;
      gsync(bar, epoch);
    }
  }
}

// ---------------------------------------------------------------------------
// attention for all (t,b): wg = (b, 16-t chunk). scores -> softmax -> ctx
__global__ __launch_bounds__(256) void k_attn(float* __restrict__ ws)
{
  const int b  = blockIdx.x >> 3;
  const int t0 = (blockIdx.x & 7) * 16;
  __shared__ float Hc[16*64];
  __shared__ float Mc[128*68];
  __shared__ float Sc[16*132];
  const int tid = threadIdx.x;
  const float* mem = ws + OFF_MEM;
  float* ffn = ws + OFF_FFN;
  const int r  = tid >> 4;
  const int si = tid & 15;
  const float scale = 0.044194173824159216f;   // 1/sqrt(512)

  float acc[8];
  #pragma unroll
  for (int q = 0; q < 8; ++q) acc[q] = 0.0f;

  for (int dc = 0; dc < 8; ++dc) {
    const int d0 = dc * 64;
    __syncthreads();
    { int rr = tid >> 4, dd = (tid & 15) * 4;
      *(float4*)&Hc[rr*64 + dd] =
          *(const float4*)&ffn[((size_t)(t0+rr)*32 + b)*1024 + d0 + dd]; }
    { int s = tid >> 1, half = (tid & 1) * 32;
      const float* src = &mem[((size_t)b*128 + s)*512 + d0 + half];
      #pragma unroll
      for (int u = 0; u < 8; ++u)
        *(float4*)&Mc[s*68 + half + u*4] = *(const float4*)&src[u*4]; }
    __syncthreads();
    #pragma unroll 4
    for (int kk = 0; kk < 64; kk += 4) {
      float4 h4 = *(const float4*)&Hc[r*64 + kk];
      #pragma unroll
      for (int q = 0; q < 8; ++q) {
        float4 m4 = *(const float4*)&Mc[(si + 16*q)*68 + kk];
        acc[q] += dot4(h4, m4);
      }
    }
  }
  #pragma unroll
  for (int q = 0; q < 8; ++q) Sc[r*132 + si + 16*q] = acc[q] * scale;
  __syncthreads();

  {
    const int w = tid >> 6, lane = tid & 63;
    for (int rr = w*4; rr < w*4 + 4; ++rr) {
      float v0 = Sc[rr*132 + lane];
      float v1 = Sc[rr*132 + 64 + lane];
      float m = fmaxf(v0, v1);
      #pragma unroll
      for (int off = 32; off >= 1; off >>= 1) m = fmaxf(m, __shfl_xor(m, off));
      float e0 = expf(v0 - m), e1 = expf(v1 - m);
      float ssum = e0 + e1;
      #pragma unroll
      for (int off = 32; off >= 1; off >>= 1) ssum += __shfl_xor(ssum, off);
      float inv = 1.0f / ssum;
      Sc[rr*132 + lane]      = e0 * inv;
      Sc[rr*132 + 64 + lane] = e1 * inv;
    }
  }

  for (int dc = 0; dc < 8; ++dc) {
    const int d0 = dc * 64;
    __syncthreads();
    { int s = tid >> 1, half = (tid & 1) * 32;
      const float* src = &mem[((size_t)b*128 + s)*512 + d0 + half];
      #pragma unroll
      for (int u = 0; u < 8; ++u)
        *(float4*)&Mc[s*68 + half + u*4] = *(const float4*)&src[u*4]; }
    __syncthreads();
    const int dd = (tid & 15) * 4;
    float4 a4; a4.x = a4.y = a4.z = a4.w = 0.0f;
    for (int s = 0; s < 128; s += 4) {
      float4 p4 = *(const float4*)&Sc[r*132 + s];
      float4 m0 = *(const float4*)&Mc[(s+0)*68 + dd];
      float4 m1 = *(const float4*)&Mc[(s+1)*68 + dd];
      float4 m2 = *(const float4*)&Mc[(s+2)*68 + dd];
      float4 m3 = *(const float4*)&Mc[(s+3)*68 + dd];
      a4.x += p4.x*m0.x + p4.y*m1.x + p4.z*m2.x + p4.w*m3.x;
      a4.y += p4.x*m0.y + p4.y*m1.y + p4.z*m2.y + p4.w*m3.y;
      a4.z += p4.x*m0.z + p4.y*m1.z + p4.z*m2.z + p4.w*m3.z;
      a4.w += p4.x*m0.w + p4.y*m1.w + p4.z*m2.w + p4.w*m3.w;
    }
    *(float4*)&ffn[((size_t)(t0+r)*32 + b)*1024 + 512 + d0 + dd] = a4;
  }
}

// ---------------------------------------------------------------------------
// f1 = lrelu(ffn @ W_f1^T + b_f1) -> split bf16 (Ahi, Alo)  [4096,1024]@[1024,512]
__global__ __launch_bounds__(256) void k_f1(
    const float* __restrict__ A, const float* __restrict__ Bm,
    const float* __restrict__ bias,
    u16* __restrict__ Ahi, u16* __restrict__ Alo)
{
  const int rt = blockIdx.x >> 2;
  const int vt = blockIdx.x & 3;
  __shared__ float As[64*44];
  __shared__ float Bs[128*44];
  const int tid = threadIdx.x, tx = tid & 15, ty = tid >> 4;
  float acc[4][8];
  #pragma unroll
  for (int i = 0; i < 4; ++i)
    #pragma unroll
    for (int j = 0; j < 8; ++j) acc[i][j] = 0.0f;

  for (int k0 = 0; k0 < 1024; k0 += 32) {
    __syncthreads();
    { int r = tid >> 2, kp = (tid & 3) * 8;
      const float* src = A + (size_t)(rt*64 + r)*1024 + k0 + kp;
      *(float4*)&As[r*44 + kp]     = ((const float4*)src)[0];
      *(float4*)&As[r*44 + kp + 4] = ((const float4*)src)[1]; }
    { int v = tid >> 1, kp = (tid & 1) * 16;
      const float* src = Bm + (size_t)(vt*128 + v)*1024 + k0 + kp;
      *(float4*)&Bs[v*44 + kp]      = ((const float4*)src)[0];
      *(float4*)&Bs[v*44 + kp + 4]  = ((const float4*)src)[1];
      *(float4*)&Bs[v*44 + kp + 8]  = ((const float4*)src)[2];
      *(float4*)&Bs[v*44 + kp + 12] = ((const float4*)src)[3]; }
    __syncthreads();
    #pragma unroll
    for (int kk = 0; kk < 32; kk += 4) {
      float4 a4[4], b4[8];
      #pragma unroll
      for (int i = 0; i < 4; ++i) a4[i] = *(const float4*)&As[(ty + 16*i)*44 + kk];
      #pragma unroll
      for (int j = 0; j < 8; ++j) b4[j] = *(const float4*)&Bs[(tx + 16*j)*44 + kk];
      #pragma unroll
      for (int i = 0; i < 4; ++i)
        #pragma unroll
        for (int j = 0; j < 8; ++j)
          acc[i][j] += dot4(a4[i], b4[j]);
    }
  }
  #pragma unroll
  for (int i = 0; i < 4; ++i) {
    int r = rt*64 + ty + 16*i;
    #pragma unroll
    for (int j = 0; j < 8; ++j) {
      int v = vt*128 + tx + 16*j;
      float val = lrelu(acc[i][j] + bias[v]);
      u16 h = f2bf(val);
      Ahi[(size_t)r*512 + v] = h;
      Alo[(size_t)r*512 + v] = f2bf(val - bf2f(h));
    }
  }
}

// ---------------------------------------------------------------------------
// W_f2 [32000x512] fp32 -> Whi/Wlo bf16 split
__global__ __launch_bounds__(256) void k_cvtW(
    const float* __restrict__ W, u16* __restrict__ Whi, u16* __restrict__ Wlo)
{
  const size_t stride = (size_t)gridDim.x * 256;
  // 8-float units: 32000*512/8 = 2,048,000
  for (size_t u = (size_t)blockIdx.x * 256 + threadIdx.x; u < 2048000; u += stride) {
    float4 w0 = ((const float4*)W)[u*2];
    float4 w1 = ((const float4*)W)[u*2 + 1];
    float vs[8] = {w0.x, w0.y, w0.z, w0.w, w1.x, w1.y, w1.z, w1.w};
    u16x8 hv, lv;
    #pragma unroll
    for (int q = 0; q < 8; ++q) {
      u16 h = f2bf(vs[q]);
      hv[q] = h;
      lv[q] = f2bf(vs[q] - bf2f(h));
    }
    *(u16x8*)&Whi[u*8] = hv;
    *(u16x8*)&Wlo[u*8] = lv;
  }
}

// ---------------------------------------------------------------------------
// logits = F1 @ W_f2^T via 3-pass split-bf16 MFMA:
//   C = Ahi*Whi^T + Ahi*Wlo^T + Alo*Whi^T      [4096,512]@[512,32000]
// block tile 64x128, 4 waves (2x2), per-wave 32x64 = 2x4 16x16 frags, BK=64.
// LDS rows are 128B (64 bf16) with 16B-seg XOR swizzle: seg ^= (row&7).
__global__ __launch_bounds__(256) void k_out2(
    const u16* __restrict__ Ahi, const u16* __restrict__ Alo,
    const u16* __restrict__ Whi, const u16* __restrict__ Wlo,
    float* __restrict__ out)
{
  __shared__ __align__(16) u16 As[2][64*64];    // 8 KB per buf
  __shared__ __align__(16) u16 Bs[2][128*64];   // 16 KB per buf (48 KB total)

  const int tid = threadIdx.x;
  const int rt = blockIdx.x & 63;       // M tile (64 rows)
  const int vt = blockIdx.x >> 6;       // N tile (128 cols)
  const int lane = tid & 63, wv = tid >> 6;
  const int wm = wv >> 1, wn = wv & 1;  // wave grid 2(M) x 2(N)
  const int lr = lane & 15, lk = lane >> 4;

  const u16* APs[3] = {Ahi, Ahi, Alo};
  const u16* BPs[3] = {Whi, Wlo, Whi};

  f32x4 acc[2][4];
  #pragma unroll
  for (int i = 0; i < 2; ++i)
    #pragma unroll
    for (int j = 0; j < 4; ++j) acc[i][j] = (f32x4){0.f, 0.f, 0.f, 0.f};

  float4 ra[2], rb[4];

  // ---- staging helpers (thread u owns 16B slots: A: u, u+256; B: u+256r) ----
  auto load_phase = [&](int ph) {
    const int pass = ph >> 3, k0 = (ph & 7) << 6;
    const u16* Ap = APs[pass];
    const u16* Bp = BPs[pass];
    #pragma unroll
    for (int q = 0; q < 2; ++q) {
      int s = tid + (q << 8);
      ra[q] = *(const float4*)&Ap[(size_t)(rt*64 + (s >> 3))*512 + k0 + ((s & 7) << 3)];
    }
    #pragma unroll
    for (int q = 0; q < 4; ++q) {
      int s = tid + (q << 8);
      rb[q] = *(const float4*)&Bp[(size_t)(vt*128 + (s >> 3))*512 + k0 + ((s & 7) << 3)];
    }
  };
  auto store_phase = [&](int buf) {
    #pragma unroll
    for (int q = 0; q < 2; ++q) {
      int s = tid + (q << 8), row = s >> 3, sg = s & 7;
      *(float4*)&As[buf][row*64 + ((sg ^ (row & 7)) << 3)] = ra[q];
    }
    #pragma unroll
    for (int q = 0; q < 4; ++q) {
      int s = tid + (q << 8), row = s >> 3, sg = s & 7;
      *(float4*)&Bs[buf][row*64 + ((sg ^ (row & 7)) << 3)] = rb[q];
    }
  };

  // prologue
  load_phase(0);
  store_phase(0);
  __syncthreads();

  for (int ph = 0; ph < 24; ++ph) {
    const int buf = ph & 1;
    if (ph < 23) load_phase(ph + 1);   // issue-early: hide HBM under MFMA

    #pragma unroll
    for (int kstep = 0; kstep < 2; ++kstep) {
      s16x8 af[2], bfr[4];
      #pragma unroll
      for (int fm = 0; fm < 2; ++fm) {
        int row = wm*32 + fm*16 + lr;
        int sg = (kstep*4 + lk) ^ (row & 7);
        af[fm] = *(const s16x8*)&As[buf][row*64 + sg*8];
      }
      #pragma unroll
      for (int fn = 0; fn < 4; ++fn) {
        int row = wn*64 + fn*16 + lr;
        int sg = (kstep*4 + lk) ^ (row & 7);
        bfr[fn] = *(const s16x8*)&Bs[buf][row*64 + sg*8];
      }
      #pragma unroll
      for (int fm = 0; fm < 2; ++fm)
        #pragma unroll
        for (int fn = 0; fn < 4; ++fn)
          acc[fm][fn] = __builtin_amdgcn_mfma_f32_16x16x32_bf16(
              af[fm], bfr[fn], acc[fm][fn], 0, 0, 0);
    }

    if (ph < 23) store_phase(buf ^ 1); // write-late (waits vmcnt via dep)
    __syncthreads();
  }

  // epilogue: D frag layout col = lane&15, row = (lane>>4)*4 + reg
  #pragma unroll
  for (int fm = 0; fm < 2; ++fm) {
    #pragma unroll
    for (int fn = 0; fn < 4; ++fn) {
      int v = vt*128 + wn*64 + fn*16 + lr;
      #pragma unroll
      for (int reg = 0; reg < 4; ++reg) {
        int n = rt*64 + wm*32 + fm*16 + lk*4 + reg;   // row = t*32 + b
        int bb = n & 31, t = n >> 5;
        out[((size_t)bb*128 + t)*32000 + v] = acc[fm][fn][reg];
      }
    }
  }
}

// ---------------------------------------------------------------------------
extern "C" void kernel_launch(void* const* d_in, const int* in_sizes, int n_in,
                              void* d_out, int out_size, void* d_ws, size_t ws_size,
                              hipStream_t stream)
{
  (void)in_sizes; (void)n_in; (void)out_size; (void)ws_size;
  const int*   inp     = (const int*)d_in[0];
  const int*   label_i = (const int*)d_in[1];
  const int*   x       = (const int*)d_in[2];
  const int*   label   = (const int*)d_in[3];
  const float* start_e = (const float*)d_in[4];
  const float* tok_emb = (const float*)d_in[5];
  const float* enc_sty = (const float*)d_in[6];
  const float* style   = (const float*)d_in[7];
  const float* Wih_f   = (const float*)d_in[8];
  const float* Whh_f   = (const float*)d_in[9];
  const float* bih_f   = (const float*)d_in[10];
  const float* bhh_f   = (const float*)d_in[11];
  const float* Wih_b   = (const float*)d_in[12];
  const float* Whh_b   = (const float*)d_in[13];
  const float* bih_b   = (const float*)d_in[14];
  const float* bhh_b   = (const float*)d_in[15];
  const float* Wih_d   = (const float*)d_in[16];
  const float* Whh_d   = (const float*)d_in[17];
  const float* bih_d   = (const float*)d_in[18];
  const float* bhh_d   = (const float*)d_in[19];
  const float* W_tr    = (const float*)d_in[20];
  const float* W_f1    = (const float*)d_in[21];
  const float* b_f1    = (const float*)d_in[22];
  const float* W_f2    = (const float*)d_in[23];
  float* ws  = (float*)d_ws;
  float* out = (float*)d_out;

  // split-bf16 storage (all inside existing workspace regions):
  //  Ahi/Alo: reuse old F1 region (f32 F1 no longer materialized)
  //  Whi: PREF+PREB region (dead after k_rec); Wlo: PRED region (dead after k_rec)
  u16* Ahi = (u16*)(ws + OFF_F1);
  u16* Alo = Ahi + 2097152;               // 4096*512
  u16* Whi = (u16*)(ws + OFF_PREF);       // 16,384,000 u16 <= 8.38M floats
  u16* Wlo = (u16*)(ws + OFF_PRED);

  k_init<<<dim3(1024), dim3(256), 0, stream>>>(inp, x, label_i, label,
                                               start_e, tok_emb, enc_sty, style, ws);
  k_pre<<<dim3(2048), dim3(256), 0, stream>>>(ws + OFF_EMBS, Wih_f, bih_f, bhh_f,
                                              ws + OFF_PREF, 1024, 0);
  k_pre<<<dim3(2048), dim3(256), 0, stream>>>(ws + OFF_EMBS, Wih_b, bih_b, bhh_b,
                                              ws + OFF_PREB, 1024, 1);
  k_pre<<<dim3(4096), dim3(256), 0, stream>>>(ws + OFF_DEMB, Wih_d, bih_d, bhh_d,
                                              ws + OFF_PRED, 2048, 0);
  k_rec<<<dim3(NWG), dim3(256), 0, stream>>>(Whh_f, Whh_b, Whh_d, W_tr, ws);
  k_attn<<<dim3(256), dim3(256), 0, stream>>>(ws);
  k_f1<<<dim3(256), dim3(256), 0, stream>>>(ws + OFF_FFN, W_f1, b_f1, Ahi, Alo);
  k_cvtW<<<dim3(2048), dim3(256), 0, stream>>>(W_f2, Whi, Wlo);
  k_out2<<<dim3(16000), dim3(256), 0, stream>>>(Ahi, Alo, Whi, Wlo, out);
}